// Round 12
// baseline (361.987 us; speedup 1.0000x reference)
//
#include <hip/hip_runtime.h>
#include <math.h>

#define N_IMG 6
#define CIN   256
#define H_IN  32
#define W_IN  88
#define SP    2816      // 32*88
#define HH    34        // H+2 halo
#define WW    90        // W+2 halo
#define SPH   3060      // 34*90
#define COUTC 80
#define EPSBN 1e-5f

typedef _Float16 half8 __attribute__((ext_vector_type(8)));
typedef float floatx4 __attribute__((ext_vector_type(4)));

#define AS1 __attribute__((address_space(1)))
#define AS3 __attribute__((address_space(3)))

// ---------------- weight prep ----------------
// w (OIHW [256][256][3][3]) -> fp16 [tap][oc][ic]; blockIdx.y picks layer
__global__ __launch_bounds__(256) void prep_w33(const float* __restrict__ wa,
                                                const float* __restrict__ wb,
                                                _Float16* __restrict__ wTa,
                                                _Float16* __restrict__ wTb) {
  __shared__ float s[2304];
  const int oc = blockIdx.x;
  const int tid = threadIdx.x;
  const float* w = blockIdx.y ? wb : wa;
  _Float16* wT = blockIdx.y ? wTb : wTa;
  const float* wo = w + (size_t)oc * 2304;
  for (int i = tid; i < 2304; i += 256) s[i] = wo[i];
  __syncthreads();
  for (int i = tid; i < 2304; i += 256) {
    const int tap = i >> 8;
    const int ic  = i & 255;
    wT[((size_t)tap * 256 + oc) * 256 + ic] = (_Float16)s[ic * 9 + tap];
  }
}

// combined: w3 cast copy (blocks 0..79) + halo zeroing of x0/x1h (blocks 80..85)
__global__ __launch_bounds__(256) void prep_misc(const float* __restrict__ w3,
                                                 _Float16* __restrict__ wT3,
                                                 _Float16* __restrict__ a,
                                                 _Float16* __restrict__ b) {
  const int bx = blockIdx.x;
  const int tid = threadIdx.x;
  if (bx < 80) {
    const int idx = bx * 256 + tid;
    wT3[idx] = (_Float16)w3[idx];
  } else {
    const int im = bx - 80;   // 0..5
    for (int s = tid; s < 244 * 32; s += 256) {
      const int pos = s >> 5;
      const int gr  = s & 31;
      int h, w;
      if (pos < 90)       { h = 0;  w = pos; }
      else if (pos < 180) { h = 33; w = pos - 90; }
      else { const int r = pos - 180; h = 1 + (r >> 1); w = (r & 1) * 89; }
      const size_t off = ((size_t)im * SPH + h * WW + w) * CIN + gr * 8;
      half8 z = {};
      *(half8*)(a + off) = z;
      *(half8*)(b + off) = z;
    }
  }
}

// img fp32 NCHW -> fp16 NHWC with zero halo ([im][34][90][256])
__global__ __launch_bounds__(256) void nchw_to_nhwc(const float* __restrict__ img,
                                                    _Float16* __restrict__ x0) {
  __shared__ float t[64][65];
  const int sp0 = blockIdx.x * 64;
  const int ic0 = blockIdx.y * 64;
  const int im  = blockIdx.z;
  const int tx = threadIdx.x & 63;
  const int ty = threadIdx.x >> 6;   // 0..3
  for (int r = ty; r < 64; r += 4)
    t[r][tx] = img[((size_t)(im * CIN + ic0 + r)) * SP + sp0 + tx];
  __syncthreads();
  for (int r = ty; r < 64; r += 4) {
    const int sp = sp0 + r;
    const int h = sp / 88;
    const int w = sp - h * 88;
    x0[((size_t)im * SPH + h * WW + w + WW + 1) * CIN + ic0 + tx] = (_Float16)t[tx][r];
  }
}

// ---------------- 3x3 conv + BN + ReLU: BK=128, B-direct-VGPR ---------------
// tile 64(M) x 128(N), grid 528 (264 M-tiles x 2 N-tiles) = 2.06 blocks/CU.
// 18 chunks of BK=128 over (tap, k-half). A: dbuf global_load_lds 2x16 KB
// (32 KB LDS only), XOR-granule swizzle. B: direct global->VGPR (L2-hot,
// shared across all M-blocks; ks=0 frags prefetched one chunk ahead — their
// drain piggybacks on the A-drain barrier). ONE barrier per chunk, 18 total.
__global__ __launch_bounds__(256) void conv3x3_mfma(
    const _Float16* __restrict__ x, const _Float16* __restrict__ wT,
    const float* __restrict__ bias, const float* __restrict__ gamma,
    const float* __restrict__ beta, const float* __restrict__ bnm,
    const float* __restrict__ bnv, _Float16* __restrict__ out,
    int OW, int OB, int imStride)
{
  __shared__ _Float16 As[2][64 * 128];   // 2 x 16 KB, [row 64][128 halfs phys-swizzled]

  const int tid  = threadIdx.x;
  const int wv   = tid >> 6;
  const int lane = tid & 63;
  const int bx   = blockIdx.x;
  const int n0   = (bx & 1) << 7;
  const int mt   = bx >> 1;            // 0..263
  const int im   = mt / 44;
  const int m0sp = (mt - im * 44) * 64;
  const _Float16* xim = x + (size_t)im * SPH * CIN;

  // A staging source offsets: 1024 granules (64 rows x 16), 4 issues/thread.
  // phys col p at (row r): logical l = (p&8) | ((p^r)&7)  (involution)
  int srcA[4];
  #pragma unroll
  for (int i = 0; i < 4; ++i) {
    const int g = i * 256 + wv * 64 + lane;
    const int r = g >> 4;
    const int p = g & 15;
    const int l = (p & 8) | ((p ^ r) & 7);
    const int m = m0sp + r;
    const int h = m / 88;
    const int w = m - h * 88;
    srcA[i] = ((h + 1) * WW + (w + 1)) * CIN + l * 8;
  }

  const int fr = lane & 15;
  const int q  = lane >> 4;        // 0..3
  const int q8 = q * 8;
  const int q4 = q * 4;
  const int mw = (wv & 1) * 32;    // wave-tile 32(M) x 64(N)
  const int nw = (wv >> 1) * 64;

  // per-wave B row bases (4 oc-frags of 16)
  const _Float16* wB[4];
  #pragma unroll
  for (int j = 0; j < 4; ++j)
    wB[j] = wT + (size_t)(n0 + nw + j * 16 + fr) * 256 + q8;

  floatx4 acc[2][4];
  #pragma unroll
  for (int i = 0; i < 2; ++i)
    #pragma unroll
    for (int j = 0; j < 4; ++j) {
      acc[i][j][0] = 0.f; acc[i][j][1] = 0.f; acc[i][j][2] = 0.f; acc[i][j][3] = 0.f;
    }

  // prologue: A-DMA chunk 0 (tap 0: dy=-1,dx=-1; icc=0); B ks=0 prefetch
  {
    const int aoff0 = (-1 * WW - 1) * CIN;
    #pragma unroll
    for (int i = 0; i < 4; ++i)
      __builtin_amdgcn_global_load_lds(
          (const AS1 void*)(xim + srcA[i] + aoff0),
          (AS3 void*)(&As[0][(i * 256 + wv * 64) * 8]), 16, 0, 0);
  }
  half8 bpre[4];
  #pragma unroll
  for (int j = 0; j < 4; ++j) bpre[j] = *(const half8*)(wB[j]);

  for (int c = 0; c < 18; ++c) {
    __syncthreads();   // drains A-DMA(c) + bpre loads; waves done with buf (c+1)&1
    if (c < 17) {
      const int cn   = c + 1;
      const int tapn = cn >> 1;
      const int iccn = (cn & 1) << 7;
      const int dyn  = tapn / 3 - 1;
      const int dxn  = tapn - (tapn / 3) * 3 - 1;
      const int aoffn = (dyn * WW + dxn) * CIN + iccn;
      const int nb = cn & 1;
      #pragma unroll
      for (int i = 0; i < 4; ++i)
        __builtin_amdgcn_global_load_lds(
            (const AS1 void*)(xim + srcA[i] + aoffn),
            (AS3 void*)(&As[nb][(i * 256 + wv * 64) * 8]), 16, 0, 0);
    }
    const int tap = c >> 1;
    const int icc = (c & 1) << 7;
    const size_t bco = (size_t)tap * 65536 + icc;
    const _Float16* Ac = As[c & 1];

    #pragma unroll
    for (int ks = 0; ks < 4; ++ks) {
      half8 af[2], bf[4];
      #pragma unroll
      for (int i = 0; i < 2; ++i) {
        const int row = mw + i * 16 + fr;
        const int l = ks * 4 + q;
        const int p = (l & 8) | ((l ^ row) & 7);
        af[i] = *(const half8*)(&Ac[row * 128 + p * 8]);
      }
      if (ks == 0) {
        #pragma unroll
        for (int j = 0; j < 4; ++j) bf[j] = bpre[j];
      } else {
        #pragma unroll
        for (int j = 0; j < 4; ++j) bf[j] = *(const half8*)(wB[j] + bco + ks * 32);
      }
      #pragma unroll
      for (int i = 0; i < 2; ++i)
        #pragma unroll
        for (int j = 0; j < 4; ++j)
          acc[i][j] = __builtin_amdgcn_mfma_f32_16x16x32_f16(af[i], bf[j], acc[i][j], 0, 0, 0);
    }

    // prefetch next chunk's ks=0 B-frags (drained by next barrier alongside A)
    if (c < 17) {
      const int cn   = c + 1;
      const size_t bcn = (size_t)(cn >> 1) * 65536 + ((cn & 1) << 7);
      #pragma unroll
      for (int j = 0; j < 4; ++j) bpre[j] = *(const half8*)(wB[j] + bcn);
    }
  }

  // epilogue: BN + ReLU, store fp16 NHWC (halo or flat per OW/OB/imStride)
  #pragma unroll
  for (int j = 0; j < 4; ++j) {
    const int oc = n0 + nw + j * 16 + fr;
    const float sc = gamma[oc] * rsqrtf(bnv[oc] + EPSBN);
    const float sh = (bias[oc] - bnm[oc]) * sc + beta[oc];
    #pragma unroll
    for (int i = 0; i < 2; ++i) {
      #pragma unroll
      for (int r = 0; r < 4; ++r) {
        const int m = m0sp + mw + i * 16 + q4 + r;
        const int h = m / 88;
        const int w = m - h * 88;
        const float v = fmaxf(fmaf(acc[i][j][r], sc, sh), 0.f);
        out[((size_t)im * imStride + h * OW + w + OB) * CIN + oc] = (_Float16)v;
      }
    }
  }
}

// ---------------- 1x1 conv (256->80) + bias, fp16 MFMA, NHWC fp16 out --------
__global__ __launch_bounds__(128) void conv1x1_mfma(
    const _Float16* __restrict__ x, const _Float16* __restrict__ wT,
    const float* __restrict__ bias, _Float16* __restrict__ feat)
{
  __shared__ _Float16 Bs[80 * 264];   // [oc][ic 256 + pad 8]

  const int tid = threadIdx.x;
  const int m0  = blockIdx.x * 64;
  const int wv   = tid >> 6;
  const int lane = tid & 63;
  const int fr  = lane & 15;
  const int q8  = (lane >> 4) * 8;
  const int q4  = (lane >> 4) * 4;

  for (int g = tid; g < 2560; g += 128) {
    const int oc = g >> 5;
    const int kg8 = (g & 31) << 3;
    *(half8*)(&Bs[oc * 264 + kg8]) = *(const half8*)(wT + oc * 256 + kg8);
  }
  __syncthreads();

  floatx4 acc[2][5];
  #pragma unroll
  for (int i = 0; i < 2; ++i)
    #pragma unroll
    for (int j = 0; j < 5; ++j) {
      acc[i][j][0] = 0.f; acc[i][j][1] = 0.f; acc[i][j][2] = 0.f; acc[i][j][3] = 0.f;
    }

  const _Float16* xa = x + (size_t)(m0 + wv * 32 + fr) * 256 + q8;
  #pragma unroll
  for (int ks = 0; ks < 8; ++ks) {
    half8 af[2], bf[5];
    #pragma unroll
    for (int i = 0; i < 2; ++i)
      af[i] = *(const half8*)(xa + (size_t)i * 16 * 256 + ks * 32);
    #pragma unroll
    for (int j = 0; j < 5; ++j)
      bf[j] = *(const half8*)(&Bs[(j * 16 + fr) * 264 + ks * 32 + q8]);
    #pragma unroll
    for (int i = 0; i < 2; ++i)
      #pragma unroll
      for (int j = 0; j < 5; ++j)
        acc[i][j] = __builtin_amdgcn_mfma_f32_16x16x32_f16(af[i], bf[j], acc[i][j], 0, 0, 0);
  }

  #pragma unroll
  for (int j = 0; j < 5; ++j) {
    const int oc = j * 16 + fr;
    const float bb = bias[oc];
    #pragma unroll
    for (int i = 0; i < 2; ++i) {
      const int mbase = m0 + wv * 32 + i * 16 + q4;
      #pragma unroll
      for (int r = 0; r < 4; ++r)
        feat[(size_t)(mbase + r) * COUTC + oc] = (_Float16)(acc[i][j][r] + bb);
    }
  }
}

// ---------------- projection + bilinear + max over cams + mean over z --------
// block: 320 threads = 32 cells x 10 channel-groups (8 ch each, half8 loads).
__global__ __launch_bounds__(320) void bev_sample(
    const _Float16* __restrict__ feat, const float* __restrict__ l2i,
    float* __restrict__ tmp)
{
  __shared__ int4   eo[1920];
  __shared__ float4 ew[1920];
  const int tid = threadIdx.x;
  const int cellBase = blockIdx.x * 32;

  for (int e = tid; e < 1920; e += 320) {
    const int cell = e / 60;
    const int idx = e - cell * 60;
    const int n = idx / 10;
    const int z = idx - n * 10;
    const int cid = cellBase + cell;
    const int gix = cid >> 7;
    const int giy = cid & 127;
    const float X = (float)(-50.8 + (double)gix * (101.6 / 127.0));
    const float Y = (float)(-50.8 + (double)giy * (101.6 / 127.0));
    const float Z = (float)(-4.6 + (double)z * (7.2 / 9.0));
    const float* M = l2i + n * 16;
    const float pw = M[0] * X + M[1] * Y + M[2] * Z + M[3];
    const float ph = M[4] * X + M[5] * Y + M[6] * Z + M[7];
    const float d  = M[8] * X + M[9] * Y + M[10] * Z + M[11];
    const float px = pw / d;
    const float py = ph / d;
    const bool on_img = (px < 704.f) && (px > 0.f) && (py < 256.f) && (py > 0.f) && (d > 0.1f);
    const float gx = px / 704.f * 2.f - 1.f;
    const float gy = py / 256.f * 2.f - 1.f;
    const float ixf = (gx + 1.f) * 0.5f * 87.f;
    const float iyf = (gy + 1.f) * 0.5f * 31.f;
    const float ix0 = floorf(ixf);
    const float iy0 = floorf(iyf);
    const float wx1 = ixf - ix0;
    const float wy1 = iyf - iy0;
    const float ix1 = ix0 + 1.f, iy1 = iy0 + 1.f;
    float w00 = (1.f - wy1) * (1.f - wx1);
    float w01 = (1.f - wy1) * wx1;
    float w10 = wy1 * (1.f - wx1);
    float w11 = wy1 * wx1;
    const bool vx0 = (ix0 >= 0.f) && (ix0 < 88.f);
    const bool vx1 = (ix1 >= 0.f) && (ix1 < 88.f);
    const bool vy0 = (iy0 >= 0.f) && (iy0 < 32.f);
    const bool vy1 = (iy1 >= 0.f) && (iy1 < 32.f);
    if (!(on_img && vy0 && vx0)) w00 = 0.f;
    if (!(on_img && vy0 && vx1)) w01 = 0.f;
    if (!(on_img && vy1 && vx0)) w10 = 0.f;
    if (!(on_img && vy1 && vx1)) w11 = 0.f;
    const int i0 = (int)fminf(fmaxf(ix0, 0.f), 87.f);
    const int i1 = (int)fminf(fmaxf(ix1, 0.f), 87.f);
    const int j0 = (int)fminf(fmaxf(iy0, 0.f), 31.f);
    const int j1 = (int)fminf(fmaxf(iy1, 0.f), 31.f);
    const int base = n * SP;
    eo[e] = make_int4((base + j0 * 88 + i0) * COUTC,
                      (base + j0 * 88 + i1) * COUTC,
                      (base + j1 * 88 + i0) * COUTC,
                      (base + j1 * 88 + i1) * COUTC);
    ew[e] = make_float4(w00, w01, w10, w11);
  }
  __syncthreads();

  const int grp  = tid % 10;
  const int c8   = grp * 8;
  const int cell = tid / 10;
  const int ebase = cell * 60;
  float acc[8];
  #pragma unroll
  for (int k = 0; k < 8; ++k) acc[k] = 0.f;

  for (int z = 0; z < 10; ++z) {
    float mx[8];
    #pragma unroll
    for (int k = 0; k < 8; ++k) mx[k] = -INFINITY;
    #pragma unroll
    for (int n = 0; n < 6; ++n) {
      const float4 w = ew[ebase + n * 10 + z];
      if (w.x + w.y + w.z + w.w > 0.f) {
        const int4 o = eo[ebase + n * 10 + z];
        const half8 p00 = *(const half8*)(feat + o.x + c8);
        const half8 p01 = *(const half8*)(feat + o.y + c8);
        const half8 p10 = *(const half8*)(feat + o.z + c8);
        const half8 p11 = *(const half8*)(feat + o.w + c8);
        #pragma unroll
        for (int k = 0; k < 8; ++k) {
          float v = w.x * (float)p00[k];
          v = fmaf(w.y, (float)p01[k], v);
          v = fmaf(w.z, (float)p10[k], v);
          v = fmaf(w.w, (float)p11[k], v);
          mx[k] = fmaxf(mx[k], v);
        }
      } else {
        #pragma unroll
        for (int k = 0; k < 8; ++k) mx[k] = fmaxf(mx[k], 0.f);
      }
    }
    #pragma unroll
    for (int k = 0; k < 8; ++k) acc[k] += mx[k];
  }
  const int cid = cellBase + cell;
  float* op = tmp + (size_t)cid * COUTC + c8;
  #pragma unroll
  for (int k = 0; k < 8; ++k) op[k] = acc[k] * 0.1f;
}

// ---------------- [16384][80] -> [80][16384] transpose ----------------
__global__ __launch_bounds__(256) void bev_transpose(const float* __restrict__ tmp,
                                                     float* __restrict__ out)
{
  __shared__ float tile[32][33];
  const int mBase = blockIdx.x * 32;
  const int cBase = blockIdx.y * 32;
  const int tx = threadIdx.x & 31;
  const int ty = threadIdx.x >> 5;   // 0..7
  for (int i = ty; i < 32; i += 8) {
    const int cc = cBase + tx;
    tile[i][tx] = (cc < COUTC) ? tmp[(size_t)(mBase + i) * COUTC + cc] : 0.f;
  }
  __syncthreads();
  for (int i = ty; i < 32; i += 8) {
    const int cc = cBase + i;
    if (cc < COUTC) out[(size_t)cc * 16384 + mBase + tx] = tile[tx][i];
  }
}

extern "C" void kernel_launch(void* const* d_in, const int* in_sizes, int n_in,
                              void* d_out, int out_size, void* d_ws, size_t ws_size,
                              hipStream_t stream)
{
  const float* img = (const float*)d_in[0];
  const float* l2i = (const float*)d_in[1];
  const float* w1  = (const float*)d_in[2];
  const float* b1  = (const float*)d_in[3];
  const float* g1  = (const float*)d_in[4];
  const float* be1 = (const float*)d_in[5];
  const float* m1  = (const float*)d_in[6];
  const float* v1  = (const float*)d_in[7];
  const float* w2  = (const float*)d_in[8];
  const float* b2  = (const float*)d_in[9];
  const float* g2  = (const float*)d_in[10];
  const float* be2 = (const float*)d_in[11];
  const float* m2  = (const float*)d_in[12];
  const float* v2  = (const float*)d_in[13];
  const float* w3  = (const float*)d_in[14];
  const float* b3  = (const float*)d_in[15];

  char* ws = (char*)d_ws;
  _Float16* wT1h = (_Float16*)ws;  ws += (size_t)9 * CIN * CIN * 2;
  _Float16* wT2h = (_Float16*)ws;  ws += (size_t)9 * CIN * CIN * 2;
  _Float16* wT3h = (_Float16*)ws;  ws += (size_t)CIN * COUTC * 2;
  _Float16* x0   = (_Float16*)ws;  ws += (size_t)N_IMG * SPH * CIN * 2;
  _Float16* x1h  = (_Float16*)ws;  ws += (size_t)N_IMG * SPH * CIN * 2;
  _Float16* x2h  = (_Float16*)ws;  ws += (size_t)N_IMG * SP * CIN * 2;
  _Float16* feat = (_Float16*)ws;  ws += (size_t)N_IMG * SP * COUTC * 2;
  float*    tmp  = (float*)ws;
  float*    outp = (float*)d_out;

  prep_misc<<<86, 256, 0, stream>>>(w3, wT3h, x0, x1h);
  prep_w33<<<dim3(256, 2), 256, 0, stream>>>(w1, w2, wT1h, wT2h);
  nchw_to_nhwc<<<dim3(44, 4, 6), 256, 0, stream>>>(img, x0);

  conv3x3_mfma<<<528, 256, 0, stream>>>(x0, wT1h, b1, g1, be1, m1, v1,
                                        x1h, WW, WW + 1, SPH);
  conv3x3_mfma<<<528, 256, 0, stream>>>(x1h, wT2h, b2, g2, be2, m2, v2,
                                        x2h, 88, 0, SP);
  conv1x1_mfma<<<264, 128, 0, stream>>>(x2h, wT3h, b3, feat);

  bev_sample<<<512, 320, 0, stream>>>(feat, l2i, tmp);
  bev_transpose<<<dim3(512, 3), 256, 0, stream>>>(tmp, outp);
}

// Round 13
// 224.194 us; speedup vs baseline: 1.6146x; 1.6146x over previous
//
#include <hip/hip_runtime.h>
#include <math.h>

#define N_IMG 6
#define CIN   256
#define H_IN  32
#define W_IN  88
#define SP    2816      // 32*88
#define HH    34        // H+2 halo
#define WW    90        // W+2 halo
#define SPH   3060      // 34*90
#define COUTC 80
#define EPSBN 1e-5f

typedef _Float16 half8 __attribute__((ext_vector_type(8)));
typedef float floatx4 __attribute__((ext_vector_type(4)));

#define AS1 __attribute__((address_space(1)))
#define AS3 __attribute__((address_space(3)))

// ---------------- weight prep ----------------
// w (OIHW [256][256][3][3]) -> fp16 [tap][oc][ic]; blockIdx.y picks layer
__global__ __launch_bounds__(256) void prep_w33(const float* __restrict__ wa,
                                                const float* __restrict__ wb,
                                                _Float16* __restrict__ wTa,
                                                _Float16* __restrict__ wTb) {
  __shared__ float s[2304];
  const int oc = blockIdx.x;
  const int tid = threadIdx.x;
  const float* w = blockIdx.y ? wb : wa;
  _Float16* wT = blockIdx.y ? wTb : wTa;
  const float* wo = w + (size_t)oc * 2304;
  for (int i = tid; i < 2304; i += 256) s[i] = wo[i];
  __syncthreads();
  for (int i = tid; i < 2304; i += 256) {
    const int tap = i >> 8;
    const int ic  = i & 255;
    wT[((size_t)tap * 256 + oc) * 256 + ic] = (_Float16)s[ic * 9 + tap];
  }
}

// combined: w3 cast copy (blocks 0..79) + halo zeroing of x0/x1h (blocks 80..85)
__global__ __launch_bounds__(256) void prep_misc(const float* __restrict__ w3,
                                                 _Float16* __restrict__ wT3,
                                                 _Float16* __restrict__ a,
                                                 _Float16* __restrict__ b) {
  const int bx = blockIdx.x;
  const int tid = threadIdx.x;
  if (bx < 80) {
    const int idx = bx * 256 + tid;
    wT3[idx] = (_Float16)w3[idx];
  } else {
    const int im = bx - 80;   // 0..5
    for (int s = tid; s < 244 * 32; s += 256) {
      const int pos = s >> 5;
      const int gr  = s & 31;
      int h, w;
      if (pos < 90)       { h = 0;  w = pos; }
      else if (pos < 180) { h = 33; w = pos - 90; }
      else { const int r = pos - 180; h = 1 + (r >> 1); w = (r & 1) * 89; }
      const size_t off = ((size_t)im * SPH + h * WW + w) * CIN + gr * 8;
      half8 z = {};
      *(half8*)(a + off) = z;
      *(half8*)(b + off) = z;
    }
  }
}

// img fp32 NCHW -> fp16 NHWC with zero halo ([im][34][90][256])
__global__ __launch_bounds__(256) void nchw_to_nhwc(const float* __restrict__ img,
                                                    _Float16* __restrict__ x0) {
  __shared__ float t[64][65];
  const int sp0 = blockIdx.x * 64;
  const int ic0 = blockIdx.y * 64;
  const int im  = blockIdx.z;
  const int tx = threadIdx.x & 63;
  const int ty = threadIdx.x >> 6;   // 0..3
  for (int r = ty; r < 64; r += 4)
    t[r][tx] = img[((size_t)(im * CIN + ic0 + r)) * SP + sp0 + tx];
  __syncthreads();
  for (int r = ty; r < 64; r += 4) {
    const int sp = sp0 + r;
    const int h = sp / 88;
    const int w = sp - h * 88;
    x0[((size_t)im * SPH + h * WW + w + WW + 1) * CIN + ic0 + tx] = (_Float16)t[tx][r];
  }
}

// ---------------- 3x3 conv + BN + ReLU: BK=128 single-buffer MFMA ----------
// tile 64(M) x 128(N), grid 528 (264 M-tiles x 2 N-tiles) = 2.06 blocks/CU.
// 18 chunks of BK=128 over (tap, k-half): HALF the barrier/drain events of
// the BK=64 version (r10), same total staged bytes, same 48 KB LDS.
// Both A and B staged via global_load_lds 16B/lane, XOR-granule swizzle
// (16 granules/row: phys p = (l&8) | ((l^row)&7), involution).
__global__ __launch_bounds__(256) void conv3x3_mfma(
    const _Float16* __restrict__ x, const _Float16* __restrict__ wT,
    const float* __restrict__ bias, const float* __restrict__ gamma,
    const float* __restrict__ beta, const float* __restrict__ bnm,
    const float* __restrict__ bnv, _Float16* __restrict__ out,
    int OW, int OB, int imStride)
{
  __shared__ _Float16 As[64 * 128];    // 16 KB, [row 64][16 granules]
  __shared__ _Float16 Bs[128 * 128];   // 32 KB, [oc 128][16 granules]

  const int tid  = threadIdx.x;
  const int wv   = tid >> 6;
  const int lane = tid & 63;
  const int bx   = blockIdx.x;
  const int n0   = (bx & 1) << 7;
  const int mt   = bx >> 1;            // 0..263
  const int im   = mt / 44;
  const int m0sp = (mt - im * 44) * 64;
  const _Float16* xim = x + (size_t)im * SPH * CIN;

  // staging source offsets (granule XOR swizzle applied on the source side)
  int srcA[4], srcB[8];
  #pragma unroll
  for (int i = 0; i < 4; ++i) {
    const int g = i * 256 + wv * 64 + lane;    // 0..1023
    const int r = g >> 4;
    const int p = g & 15;
    const int l = (p & 8) | ((p ^ r) & 7);
    const int m = m0sp + r;
    const int h = m / 88;
    const int w = m - h * 88;
    srcA[i] = ((h + 1) * WW + (w + 1)) * CIN + l * 8;
  }
  #pragma unroll
  for (int i = 0; i < 8; ++i) {
    const int g = i * 256 + wv * 64 + lane;    // 0..2047
    const int r = g >> 4;
    const int p = g & 15;
    const int l = (p & 8) | ((p ^ r) & 7);
    srcB[i] = (n0 + r) * 256 + l * 8;
  }

  const int fr = lane & 15;
  const int q  = lane >> 4;        // 0..3
  const int q4 = q * 4;
  const int mw = (wv & 1) * 32;    // wave-tile 32(M) x 64(N)
  const int nw = (wv >> 1) * 64;

  floatx4 acc[2][4];
  #pragma unroll
  for (int i = 0; i < 2; ++i)
    #pragma unroll
    for (int j = 0; j < 4; ++j) {
      acc[i][j][0] = 0.f; acc[i][j][1] = 0.f; acc[i][j][2] = 0.f; acc[i][j][3] = 0.f;
    }

  for (int c = 0; c < 18; ++c) {
    const int tap = c >> 1;
    const int icc = (c & 1) << 7;
    const int dy  = tap / 3 - 1;
    const int dx  = tap - (tap / 3) * 3 - 1;
    const int aoff = (dy * WW + dx) * CIN + icc;
    const size_t boff = (size_t)tap * 65536 + icc;

    #pragma unroll
    for (int i = 0; i < 4; ++i)
      __builtin_amdgcn_global_load_lds(
          (const AS1 void*)(xim + srcA[i] + aoff),
          (AS3 void*)(&As[(i * 256 + wv * 64) * 8]), 16, 0, 0);
    #pragma unroll
    for (int i = 0; i < 8; ++i)
      __builtin_amdgcn_global_load_lds(
          (const AS1 void*)(wT + boff + srcB[i]),
          (AS3 void*)(&Bs[(i * 256 + wv * 64) * 8]), 16, 0, 0);
    __syncthreads();   // drain DMA

    #pragma unroll
    for (int ks = 0; ks < 4; ++ks) {
      const int l = ks * 4 + q;
      half8 af[2], bf[4];
      #pragma unroll
      for (int i = 0; i < 2; ++i) {
        const int row = mw + i * 16 + fr;
        const int p = (l & 8) | ((l ^ row) & 7);
        af[i] = *(const half8*)(&As[row * 128 + p * 8]);
      }
      #pragma unroll
      for (int j = 0; j < 4; ++j) {
        const int row = nw + j * 16 + fr;
        const int p = (l & 8) | ((l ^ row) & 7);
        bf[j] = *(const half8*)(&Bs[row * 128 + p * 8]);
      }
      #pragma unroll
      for (int i = 0; i < 2; ++i)
        #pragma unroll
        for (int j = 0; j < 4; ++j)
          acc[i][j] = __builtin_amdgcn_mfma_f32_16x16x32_f16(af[i], bf[j], acc[i][j], 0, 0, 0);
    }
    __syncthreads();   // LDS reuse guard
  }

  // epilogue: BN + ReLU, store fp16 NHWC (halo or flat per OW/OB/imStride)
  #pragma unroll
  for (int j = 0; j < 4; ++j) {
    const int oc = n0 + nw + j * 16 + fr;
    const float sc = gamma[oc] * rsqrtf(bnv[oc] + EPSBN);
    const float sh = (bias[oc] - bnm[oc]) * sc + beta[oc];
    #pragma unroll
    for (int i = 0; i < 2; ++i) {
      #pragma unroll
      for (int r = 0; r < 4; ++r) {
        const int m = m0sp + mw + i * 16 + q4 + r;
        const int h = m / 88;
        const int w = m - h * 88;
        const float v = fmaxf(fmaf(acc[i][j][r], sc, sh), 0.f);
        out[((size_t)im * imStride + h * OW + w + OB) * CIN + oc] = (_Float16)v;
      }
    }
  }
}

// ---------------- 1x1 conv (256->80) + bias, fp16 MFMA, NHWC fp16 out --------
__global__ __launch_bounds__(128) void conv1x1_mfma(
    const _Float16* __restrict__ x, const _Float16* __restrict__ wT,
    const float* __restrict__ bias, _Float16* __restrict__ feat)
{
  __shared__ _Float16 Bs[80 * 264];   // [oc][ic 256 + pad 8]

  const int tid = threadIdx.x;
  const int m0  = blockIdx.x * 64;
  const int wv   = tid >> 6;
  const int lane = tid & 63;
  const int fr  = lane & 15;
  const int q8  = (lane >> 4) * 8;
  const int q4  = (lane >> 4) * 4;

  for (int g = tid; g < 2560; g += 128) {
    const int oc = g >> 5;
    const int kg8 = (g & 31) << 3;
    *(half8*)(&Bs[oc * 264 + kg8]) = *(const half8*)(wT + oc * 256 + kg8);
  }
  __syncthreads();

  floatx4 acc[2][5];
  #pragma unroll
  for (int i = 0; i < 2; ++i)
    #pragma unroll
    for (int j = 0; j < 5; ++j) {
      acc[i][j][0] = 0.f; acc[i][j][1] = 0.f; acc[i][j][2] = 0.f; acc[i][j][3] = 0.f;
    }

  const _Float16* xa = x + (size_t)(m0 + wv * 32 + fr) * 256 + q8;
  #pragma unroll
  for (int ks = 0; ks < 8; ++ks) {
    half8 af[2], bf[5];
    #pragma unroll
    for (int i = 0; i < 2; ++i)
      af[i] = *(const half8*)(xa + (size_t)i * 16 * 256 + ks * 32);
    #pragma unroll
    for (int j = 0; j < 5; ++j)
      bf[j] = *(const half8*)(&Bs[(j * 16 + fr) * 264 + ks * 32 + q8]);
    #pragma unroll
    for (int i = 0; i < 2; ++i)
      #pragma unroll
      for (int j = 0; j < 5; ++j)
        acc[i][j] = __builtin_amdgcn_mfma_f32_16x16x32_f16(af[i], bf[j], acc[i][j], 0, 0, 0);
  }

  #pragma unroll
  for (int j = 0; j < 5; ++j) {
    const int oc = j * 16 + fr;
    const float bb = bias[oc];
    #pragma unroll
    for (int i = 0; i < 2; ++i) {
      const int mbase = m0 + wv * 32 + i * 16 + q4;
      #pragma unroll
      for (int r = 0; r < 4; ++r)
        feat[(size_t)(mbase + r) * COUTC + oc] = (_Float16)(acc[i][j][r] + bb);
    }
  }
}

// ---------------- projection + bilinear + max over cams + mean over z --------
// block: 320 threads = 32 cells x 10 channel-groups (8 ch each, half8 loads).
__global__ __launch_bounds__(320) void bev_sample(
    const _Float16* __restrict__ feat, const float* __restrict__ l2i,
    float* __restrict__ tmp)
{
  __shared__ int4   eo[1920];
  __shared__ float4 ew[1920];
  const int tid = threadIdx.x;
  const int cellBase = blockIdx.x * 32;

  for (int e = tid; e < 1920; e += 320) {
    const int cell = e / 60;
    const int idx = e - cell * 60;
    const int n = idx / 10;
    const int z = idx - n * 10;
    const int cid = cellBase + cell;
    const int gix = cid >> 7;
    const int giy = cid & 127;
    const float X = (float)(-50.8 + (double)gix * (101.6 / 127.0));
    const float Y = (float)(-50.8 + (double)giy * (101.6 / 127.0));
    const float Z = (float)(-4.6 + (double)z * (7.2 / 9.0));
    const float* M = l2i + n * 16;
    const float pw = M[0] * X + M[1] * Y + M[2] * Z + M[3];
    const float ph = M[4] * X + M[5] * Y + M[6] * Z + M[7];
    const float d  = M[8] * X + M[9] * Y + M[10] * Z + M[11];
    const float px = pw / d;
    const float py = ph / d;
    const bool on_img = (px < 704.f) && (px > 0.f) && (py < 256.f) && (py > 0.f) && (d > 0.1f);
    const float gx = px / 704.f * 2.f - 1.f;
    const float gy = py / 256.f * 2.f - 1.f;
    const float ixf = (gx + 1.f) * 0.5f * 87.f;
    const float iyf = (gy + 1.f) * 0.5f * 31.f;
    const float ix0 = floorf(ixf);
    const float iy0 = floorf(iyf);
    const float wx1 = ixf - ix0;
    const float wy1 = iyf - iy0;
    const float ix1 = ix0 + 1.f, iy1 = iy0 + 1.f;
    float w00 = (1.f - wy1) * (1.f - wx1);
    float w01 = (1.f - wy1) * wx1;
    float w10 = wy1 * (1.f - wx1);
    float w11 = wy1 * wx1;
    const bool vx0 = (ix0 >= 0.f) && (ix0 < 88.f);
    const bool vx1 = (ix1 >= 0.f) && (ix1 < 88.f);
    const bool vy0 = (iy0 >= 0.f) && (iy0 < 32.f);
    const bool vy1 = (iy1 >= 0.f) && (iy1 < 32.f);
    if (!(on_img && vy0 && vx0)) w00 = 0.f;
    if (!(on_img && vy0 && vx1)) w01 = 0.f;
    if (!(on_img && vy1 && vx0)) w10 = 0.f;
    if (!(on_img && vy1 && vx1)) w11 = 0.f;
    const int i0 = (int)fminf(fmaxf(ix0, 0.f), 87.f);
    const int i1 = (int)fminf(fmaxf(ix1, 0.f), 87.f);
    const int j0 = (int)fminf(fmaxf(iy0, 0.f), 31.f);
    const int j1 = (int)fminf(fmaxf(iy1, 0.f), 31.f);
    const int base = n * SP;
    eo[e] = make_int4((base + j0 * 88 + i0) * COUTC,
                      (base + j0 * 88 + i1) * COUTC,
                      (base + j1 * 88 + i0) * COUTC,
                      (base + j1 * 88 + i1) * COUTC);
    ew[e] = make_float4(w00, w01, w10, w11);
  }
  __syncthreads();

  const int grp  = tid % 10;
  const int c8   = grp * 8;
  const int cell = tid / 10;
  const int ebase = cell * 60;
  float acc[8];
  #pragma unroll
  for (int k = 0; k < 8; ++k) acc[k] = 0.f;

  for (int z = 0; z < 10; ++z) {
    float mx[8];
    #pragma unroll
    for (int k = 0; k < 8; ++k) mx[k] = -INFINITY;
    #pragma unroll
    for (int n = 0; n < 6; ++n) {
      const float4 w = ew[ebase + n * 10 + z];
      if (w.x + w.y + w.z + w.w > 0.f) {
        const int4 o = eo[ebase + n * 10 + z];
        const half8 p00 = *(const half8*)(feat + o.x + c8);
        const half8 p01 = *(const half8*)(feat + o.y + c8);
        const half8 p10 = *(const half8*)(feat + o.z + c8);
        const half8 p11 = *(const half8*)(feat + o.w + c8);
        #pragma unroll
        for (int k = 0; k < 8; ++k) {
          float v = w.x * (float)p00[k];
          v = fmaf(w.y, (float)p01[k], v);
          v = fmaf(w.z, (float)p10[k], v);
          v = fmaf(w.w, (float)p11[k], v);
          mx[k] = fmaxf(mx[k], v);
        }
      } else {
        #pragma unroll
        for (int k = 0; k < 8; ++k) mx[k] = fmaxf(mx[k], 0.f);
      }
    }
    #pragma unroll
    for (int k = 0; k < 8; ++k) acc[k] += mx[k];
  }
  const int cid = cellBase + cell;
  float* op = tmp + (size_t)cid * COUTC + c8;
  #pragma unroll
  for (int k = 0; k < 8; ++k) op[k] = acc[k] * 0.1f;
}

// ---------------- [16384][80] -> [80][16384] transpose ----------------
__global__ __launch_bounds__(256) void bev_transpose(const float* __restrict__ tmp,
                                                     float* __restrict__ out)
{
  __shared__ float tile[32][33];
  const int mBase = blockIdx.x * 32;
  const int cBase = blockIdx.y * 32;
  const int tx = threadIdx.x & 31;
  const int ty = threadIdx.x >> 5;   // 0..7
  for (int i = ty; i < 32; i += 8) {
    const int cc = cBase + tx;
    tile[i][tx] = (cc < COUTC) ? tmp[(size_t)(mBase + i) * COUTC + cc] : 0.f;
  }
  __syncthreads();
  for (int i = ty; i < 32; i += 8) {
    const int cc = cBase + i;
    if (cc < COUTC) out[(size_t)cc * 16384 + mBase + tx] = tile[tx][i];
  }
}

extern "C" void kernel_launch(void* const* d_in, const int* in_sizes, int n_in,
                              void* d_out, int out_size, void* d_ws, size_t ws_size,
                              hipStream_t stream)
{
  const float* img = (const float*)d_in[0];
  const float* l2i = (const float*)d_in[1];
  const float* w1  = (const float*)d_in[2];
  const float* b1  = (const float*)d_in[3];
  const float* g1  = (const float*)d_in[4];
  const float* be1 = (const float*)d_in[5];
  const float* m1  = (const float*)d_in[6];
  const float* v1  = (const float*)d_in[7];
  const float* w2  = (const float*)d_in[8];
  const float* b2  = (const float*)d_in[9];
  const float* g2  = (const float*)d_in[10];
  const float* be2 = (const float*)d_in[11];
  const float* m2  = (const float*)d_in[12];
  const float* v2  = (const float*)d_in[13];
  const float* w3  = (const float*)d_in[14];
  const float* b3  = (const float*)d_in[15];

  char* ws = (char*)d_ws;
  _Float16* wT1h = (_Float16*)ws;  ws += (size_t)9 * CIN * CIN * 2;
  _Float16* wT2h = (_Float16*)ws;  ws += (size_t)9 * CIN * CIN * 2;
  _Float16* wT3h = (_Float16*)ws;  ws += (size_t)CIN * COUTC * 2;
  _Float16* x0   = (_Float16*)ws;  ws += (size_t)N_IMG * SPH * CIN * 2;
  _Float16* x1h  = (_Float16*)ws;  ws += (size_t)N_IMG * SPH * CIN * 2;
  _Float16* x2h  = (_Float16*)ws;  ws += (size_t)N_IMG * SP * CIN * 2;
  _Float16* feat = (_Float16*)ws;  ws += (size_t)N_IMG * SP * COUTC * 2;
  float*    tmp  = (float*)ws;
  float*    outp = (float*)d_out;

  prep_misc<<<86, 256, 0, stream>>>(w3, wT3h, x0, x1h);
  prep_w33<<<dim3(256, 2), 256, 0, stream>>>(w1, w2, wT1h, wT2h);
  nchw_to_nhwc<<<dim3(44, 4, 6), 256, 0, stream>>>(img, x0);

  conv3x3_mfma<<<528, 256, 0, stream>>>(x0, wT1h, b1, g1, be1, m1, v1,
                                        x1h, WW, WW + 1, SPH);
  conv3x3_mfma<<<528, 256, 0, stream>>>(x1h, wT2h, b2, g2, be2, m2, v2,
                                        x2h, 88, 0, SP);
  conv1x1_mfma<<<264, 128, 0, stream>>>(x2h, wT3h, b3, feat);

  bev_sample<<<512, 320, 0, stream>>>(feat, l2i, tmp);
  bev_transpose<<<dim3(512, 3), 256, 0, stream>>>(tmp, outp);
}

// Round 14
// 219.779 us; speedup vs baseline: 1.6470x; 1.0201x over previous
//
#include <hip/hip_runtime.h>
#include <math.h>

#define N_IMG 6
#define CIN   256
#define H_IN  32
#define W_IN  88
#define SP    2816      // 32*88
#define HH    34        // H+2 halo
#define WW    90        // W+2 halo
#define SPH   3060      // 34*90
#define COUTC 80
#define EPSBN 1e-5f

typedef _Float16 half8 __attribute__((ext_vector_type(8)));
typedef float floatx4 __attribute__((ext_vector_type(4)));

#define AS1 __attribute__((address_space(1)))
#define AS3 __attribute__((address_space(3)))

// ---------------- weight prep ----------------
// w (OIHW [256][256][3][3]) -> fp16 [tap][oc][ic]; blockIdx.y picks layer
__global__ __launch_bounds__(256) void prep_w33(const float* __restrict__ wa,
                                                const float* __restrict__ wb,
                                                _Float16* __restrict__ wTa,
                                                _Float16* __restrict__ wTb) {
  __shared__ float s[2304];
  const int oc = blockIdx.x;
  const int tid = threadIdx.x;
  const float* w = blockIdx.y ? wb : wa;
  _Float16* wT = blockIdx.y ? wTb : wTa;
  const float* wo = w + (size_t)oc * 2304;
  for (int i = tid; i < 2304; i += 256) s[i] = wo[i];
  __syncthreads();
  for (int i = tid; i < 2304; i += 256) {
    const int tap = i >> 8;
    const int ic  = i & 255;
    wT[((size_t)tap * 256 + oc) * 256 + ic] = (_Float16)s[ic * 9 + tap];
  }
}

// combined: w3 cast copy (blocks 0..79) + halo zeroing of x0/x1h (blocks 80..85)
__global__ __launch_bounds__(256) void prep_misc(const float* __restrict__ w3,
                                                 _Float16* __restrict__ wT3,
                                                 _Float16* __restrict__ a,
                                                 _Float16* __restrict__ b) {
  const int bx = blockIdx.x;
  const int tid = threadIdx.x;
  if (bx < 80) {
    const int idx = bx * 256 + tid;
    wT3[idx] = (_Float16)w3[idx];
  } else {
    const int im = bx - 80;   // 0..5
    for (int s = tid; s < 244 * 32; s += 256) {
      const int pos = s >> 5;
      const int gr  = s & 31;
      int h, w;
      if (pos < 90)       { h = 0;  w = pos; }
      else if (pos < 180) { h = 33; w = pos - 90; }
      else { const int r = pos - 180; h = 1 + (r >> 1); w = (r & 1) * 89; }
      const size_t off = ((size_t)im * SPH + h * WW + w) * CIN + gr * 8;
      half8 z = {};
      *(half8*)(a + off) = z;
      *(half8*)(b + off) = z;
    }
  }
}

// img fp32 NCHW -> fp16 NHWC with zero halo ([im][34][90][256])
__global__ __launch_bounds__(256) void nchw_to_nhwc(const float* __restrict__ img,
                                                    _Float16* __restrict__ x0) {
  __shared__ float t[64][65];
  const int sp0 = blockIdx.x * 64;
  const int ic0 = blockIdx.y * 64;
  const int im  = blockIdx.z;
  const int tx = threadIdx.x & 63;
  const int ty = threadIdx.x >> 6;   // 0..3
  for (int r = ty; r < 64; r += 4)
    t[r][tx] = img[((size_t)(im * CIN + ic0 + r)) * SP + sp0 + tx];
  __syncthreads();
  for (int r = ty; r < 64; r += 4) {
    const int sp = sp0 + r;
    const int h = sp / 88;
    const int w = sp - h * 88;
    x0[((size_t)im * SPH + h * WW + w + WW + 1) * CIN + ic0 + tx] = (_Float16)t[tx][r];
  }
}

// ---------------- 3x3 conv + BN + ReLU: dbuf + co-resident MFMA ------------
// [r10, best measured: 43.5 us, 0 conflicts] tile 64(M) x 128(N), grid 528
// (2.06 blocks/CU). 36 chunks BK=64 (tap, ic-quarter). Double-buffered LDS
// (A 8K + B 16K per buf = 48 KB): DMA(c+1) issued right after the barrier,
// compute(c) overlaps; ONE barrier per chunk. XOR-granule swizzle.
__global__ __launch_bounds__(256) void conv3x3_mfma(
    const _Float16* __restrict__ x, const _Float16* __restrict__ wT,
    const float* __restrict__ bias, const float* __restrict__ gamma,
    const float* __restrict__ beta, const float* __restrict__ bnm,
    const float* __restrict__ bnv, _Float16* __restrict__ out,
    int OW, int OB, int imStride)
{
  __shared__ _Float16 As[2][64 * 64];    // 2 x 8 KB
  __shared__ _Float16 Bs[2][128 * 64];   // 2 x 16 KB

  const int tid  = threadIdx.x;
  const int wv   = tid >> 6;
  const int lane = tid & 63;
  const int bx   = blockIdx.x;
  const int n0   = (bx & 1) << 7;
  const int mt   = bx >> 1;            // 0..263
  const int im   = mt / 44;
  const int m0sp = (mt - im * 44) * 64;
  const _Float16* xim = x + (size_t)im * SPH * CIN;

  // staging source offsets (granule XOR swizzle applied on the source)
  int srcA[2], srcB[4];
  #pragma unroll
  for (int i = 0; i < 2; ++i) {
    const int g = i * 256 + wv * 64 + lane;    // 0..511
    const int row = g >> 3;
    const int lg  = (g & 7) ^ (row & 7);
    const int m = m0sp + row;
    const int h = m / 88;
    const int w = m - h * 88;
    srcA[i] = ((h + 1) * WW + (w + 1)) * CIN + lg * 8;
  }
  #pragma unroll
  for (int i = 0; i < 4; ++i) {
    const int g = i * 256 + wv * 64 + lane;    // 0..1023
    const int row = g >> 3;
    const int lg  = (g & 7) ^ (row & 7);
    srcB[i] = (n0 + row) * 256 + lg * 8;
  }

  const int fr = lane & 15;
  const int q  = lane >> 4;        // 0..3
  const int q4 = q * 4;
  const int mw = (wv & 1) * 32;
  const int nw = (wv >> 1) * 64;

  floatx4 acc[2][4];
  #pragma unroll
  for (int i = 0; i < 2; ++i)
    #pragma unroll
    for (int j = 0; j < 4; ++j) {
      acc[i][j][0] = 0.f; acc[i][j][1] = 0.f; acc[i][j][2] = 0.f; acc[i][j][3] = 0.f;
    }

  // prologue: DMA chunk 0 (tap 0: dy=-1,dx=-1; icc=0) into buffer 0
  {
    const int aoff0 = (-1 * WW - 1) * CIN;
    #pragma unroll
    for (int i = 0; i < 2; ++i)
      __builtin_amdgcn_global_load_lds(
          (const AS1 void*)(xim + srcA[i] + aoff0),
          (AS3 void*)(&As[0][(i * 256 + wv * 64) * 8]), 16, 0, 0);
    #pragma unroll
    for (int i = 0; i < 4; ++i)
      __builtin_amdgcn_global_load_lds(
          (const AS1 void*)(wT + srcB[i]),
          (AS3 void*)(&Bs[0][(i * 256 + wv * 64) * 8]), 16, 0, 0);
  }

  for (int c = 0; c < 36; ++c) {
    __syncthreads();   // drains DMA(c); all waves done reading buf (c+1)&1
    if (c < 35) {
      const int cn   = c + 1;
      const int tapn = cn >> 2;
      const int iccn = (cn & 3) << 6;
      const int dyn  = tapn / 3 - 1;
      const int dxn  = tapn - (tapn / 3) * 3 - 1;
      const int aoffn = (dyn * WW + dxn) * CIN + iccn;
      const size_t boffn = (size_t)tapn * 65536 + iccn;
      const int nb = cn & 1;
      #pragma unroll
      for (int i = 0; i < 2; ++i)
        __builtin_amdgcn_global_load_lds(
            (const AS1 void*)(xim + srcA[i] + aoffn),
            (AS3 void*)(&As[nb][(i * 256 + wv * 64) * 8]), 16, 0, 0);
      #pragma unroll
      for (int i = 0; i < 4; ++i)
        __builtin_amdgcn_global_load_lds(
            (const AS1 void*)(wT + boffn + srcB[i]),
            (AS3 void*)(&Bs[nb][(i * 256 + wv * 64) * 8]), 16, 0, 0);
    }
    const int cb = c & 1;
    #pragma unroll
    for (int ks = 0; ks < 2; ++ks) {
      half8 af[2], bf[4];
      #pragma unroll
      for (int i = 0; i < 2; ++i) {
        const int row = mw + i * 16 + fr;
        af[i] = *(const half8*)(&As[cb][row * 64 + (((ks * 4 + q) ^ (row & 7)) * 8)]);
      }
      #pragma unroll
      for (int j = 0; j < 4; ++j) {
        const int row = nw + j * 16 + fr;
        bf[j] = *(const half8*)(&Bs[cb][row * 64 + (((ks * 4 + q) ^ (row & 7)) * 8)]);
      }
      #pragma unroll
      for (int i = 0; i < 2; ++i)
        #pragma unroll
        for (int j = 0; j < 4; ++j)
          acc[i][j] = __builtin_amdgcn_mfma_f32_16x16x32_f16(af[i], bf[j], acc[i][j], 0, 0, 0);
    }
  }

  // epilogue: BN + ReLU, store fp16 NHWC (halo or flat per OW/OB/imStride)
  #pragma unroll
  for (int j = 0; j < 4; ++j) {
    const int oc = n0 + nw + j * 16 + fr;
    const float sc = gamma[oc] * rsqrtf(bnv[oc] + EPSBN);
    const float sh = (bias[oc] - bnm[oc]) * sc + beta[oc];
    #pragma unroll
    for (int i = 0; i < 2; ++i) {
      #pragma unroll
      for (int r = 0; r < 4; ++r) {
        const int m = m0sp + mw + i * 16 + q4 + r;
        const int h = m / 88;
        const int w = m - h * 88;
        const float v = fmaxf(fmaf(acc[i][j][r], sc, sh), 0.f);
        out[((size_t)im * imStride + h * OW + w + OB) * CIN + oc] = (_Float16)v;
      }
    }
  }
}

// ---------------- 1x1 conv (256->80) + bias, fp16 MFMA, NHWC fp16 out --------
__global__ __launch_bounds__(128) void conv1x1_mfma(
    const _Float16* __restrict__ x, const _Float16* __restrict__ wT,
    const float* __restrict__ bias, _Float16* __restrict__ feat)
{
  __shared__ _Float16 Bs[80 * 264];   // [oc][ic 256 + pad 8]

  const int tid = threadIdx.x;
  const int m0  = blockIdx.x * 64;
  const int wv   = tid >> 6;
  const int lane = tid & 63;
  const int fr  = lane & 15;
  const int q8  = (lane >> 4) * 8;
  const int q4  = (lane >> 4) * 4;

  for (int g = tid; g < 2560; g += 128) {
    const int oc = g >> 5;
    const int kg8 = (g & 31) << 3;
    *(half8*)(&Bs[oc * 264 + kg8]) = *(const half8*)(wT + oc * 256 + kg8);
  }
  __syncthreads();

  floatx4 acc[2][5];
  #pragma unroll
  for (int i = 0; i < 2; ++i)
    #pragma unroll
    for (int j = 0; j < 5; ++j) {
      acc[i][j][0] = 0.f; acc[i][j][1] = 0.f; acc[i][j][2] = 0.f; acc[i][j][3] = 0.f;
    }

  const _Float16* xa = x + (size_t)(m0 + wv * 32 + fr) * 256 + q8;
  #pragma unroll
  for (int ks = 0; ks < 8; ++ks) {
    half8 af[2], bf[5];
    #pragma unroll
    for (int i = 0; i < 2; ++i)
      af[i] = *(const half8*)(xa + (size_t)i * 16 * 256 + ks * 32);
    #pragma unroll
    for (int j = 0; j < 5; ++j)
      bf[j] = *(const half8*)(&Bs[(j * 16 + fr) * 264 + ks * 32 + q8]);
    #pragma unroll
    for (int i = 0; i < 2; ++i)
      #pragma unroll
      for (int j = 0; j < 5; ++j)
        acc[i][j] = __builtin_amdgcn_mfma_f32_16x16x32_f16(af[i], bf[j], acc[i][j], 0, 0, 0);
  }

  #pragma unroll
  for (int j = 0; j < 5; ++j) {
    const int oc = j * 16 + fr;
    const float bb = bias[oc];
    #pragma unroll
    for (int i = 0; i < 2; ++i) {
      const int mbase = m0 + wv * 32 + i * 16 + q4;
      #pragma unroll
      for (int r = 0; r < 4; ++r)
        feat[(size_t)(mbase + r) * COUTC + oc] = (_Float16)(acc[i][j][r] + bb);
    }
  }
}

// ---------------- projection + bilinear + max(cams) + mean(z), fused T ------
// block: 320 threads = 32 cells x 10 channel-groups (8 ch each, half8 loads).
// Writes out[c][cell] (transposed) directly — bev_transpose eliminated.
__global__ __launch_bounds__(320) void bev_sample(
    const _Float16* __restrict__ feat, const float* __restrict__ l2i,
    float* __restrict__ outp)
{
  __shared__ int4   eo[1920];
  __shared__ float4 ew[1920];
  const int tid = threadIdx.x;
  const int cellBase = blockIdx.x * 32;

  for (int e = tid; e < 1920; e += 320) {
    const int cell = e / 60;
    const int idx = e - cell * 60;
    const int n = idx / 10;
    const int z = idx - n * 10;
    const int cid = cellBase + cell;
    const int gix = cid >> 7;
    const int giy = cid & 127;
    const float X = (float)(-50.8 + (double)gix * (101.6 / 127.0));
    const float Y = (float)(-50.8 + (double)giy * (101.6 / 127.0));
    const float Z = (float)(-4.6 + (double)z * (7.2 / 9.0));
    const float* M = l2i + n * 16;
    const float pw = M[0] * X + M[1] * Y + M[2] * Z + M[3];
    const float ph = M[4] * X + M[5] * Y + M[6] * Z + M[7];
    const float d  = M[8] * X + M[9] * Y + M[10] * Z + M[11];
    const float px = pw / d;
    const float py = ph / d;
    const bool on_img = (px < 704.f) && (px > 0.f) && (py < 256.f) && (py > 0.f) && (d > 0.1f);
    const float gx = px / 704.f * 2.f - 1.f;
    const float gy = py / 256.f * 2.f - 1.f;
    const float ixf = (gx + 1.f) * 0.5f * 87.f;
    const float iyf = (gy + 1.f) * 0.5f * 31.f;
    const float ix0 = floorf(ixf);
    const float iy0 = floorf(iyf);
    const float wx1 = ixf - ix0;
    const float wy1 = iyf - iy0;
    const float ix1 = ix0 + 1.f, iy1 = iy0 + 1.f;
    float w00 = (1.f - wy1) * (1.f - wx1);
    float w01 = (1.f - wy1) * wx1;
    float w10 = wy1 * (1.f - wx1);
    float w11 = wy1 * wx1;
    const bool vx0 = (ix0 >= 0.f) && (ix0 < 88.f);
    const bool vx1 = (ix1 >= 0.f) && (ix1 < 88.f);
    const bool vy0 = (iy0 >= 0.f) && (iy0 < 32.f);
    const bool vy1 = (iy1 >= 0.f) && (iy1 < 32.f);
    if (!(on_img && vy0 && vx0)) w00 = 0.f;
    if (!(on_img && vy0 && vx1)) w01 = 0.f;
    if (!(on_img && vy1 && vx0)) w10 = 0.f;
    if (!(on_img && vy1 && vx1)) w11 = 0.f;
    const int i0 = (int)fminf(fmaxf(ix0, 0.f), 87.f);
    const int i1 = (int)fminf(fmaxf(ix1, 0.f), 87.f);
    const int j0 = (int)fminf(fmaxf(iy0, 0.f), 31.f);
    const int j1 = (int)fminf(fmaxf(iy1, 0.f), 31.f);
    const int base = n * SP;
    eo[e] = make_int4((base + j0 * 88 + i0) * COUTC,
                      (base + j0 * 88 + i1) * COUTC,
                      (base + j1 * 88 + i0) * COUTC,
                      (base + j1 * 88 + i1) * COUTC);
    ew[e] = make_float4(w00, w01, w10, w11);
  }
  __syncthreads();

  const int grp  = tid % 10;
  const int c8   = grp * 8;
  const int cell = tid / 10;
  const int ebase = cell * 60;
  float acc[8];
  #pragma unroll
  for (int k = 0; k < 8; ++k) acc[k] = 0.f;

  for (int z = 0; z < 10; ++z) {
    float mx[8];
    #pragma unroll
    for (int k = 0; k < 8; ++k) mx[k] = -INFINITY;
    #pragma unroll
    for (int n = 0; n < 6; ++n) {
      const float4 w = ew[ebase + n * 10 + z];
      if (w.x + w.y + w.z + w.w > 0.f) {
        const int4 o = eo[ebase + n * 10 + z];
        const half8 p00 = *(const half8*)(feat + o.x + c8);
        const half8 p01 = *(const half8*)(feat + o.y + c8);
        const half8 p10 = *(const half8*)(feat + o.z + c8);
        const half8 p11 = *(const half8*)(feat + o.w + c8);
        #pragma unroll
        for (int k = 0; k < 8; ++k) {
          float v = w.x * (float)p00[k];
          v = fmaf(w.y, (float)p01[k], v);
          v = fmaf(w.z, (float)p10[k], v);
          v = fmaf(w.w, (float)p11[k], v);
          mx[k] = fmaxf(mx[k], v);
        }
      } else {
        #pragma unroll
        for (int k = 0; k < 8; ++k) mx[k] = fmaxf(mx[k], 0.f);
      }
    }
    #pragma unroll
    for (int k = 0; k < 8; ++k) acc[k] += mx[k];
  }
  const int cid = cellBase + cell;
  #pragma unroll
  for (int k = 0; k < 8; ++k)
    outp[(size_t)(c8 + k) * 16384 + cid] = acc[k] * 0.1f;
}

extern "C" void kernel_launch(void* const* d_in, const int* in_sizes, int n_in,
                              void* d_out, int out_size, void* d_ws, size_t ws_size,
                              hipStream_t stream)
{
  const float* img = (const float*)d_in[0];
  const float* l2i = (const float*)d_in[1];
  const float* w1  = (const float*)d_in[2];
  const float* b1  = (const float*)d_in[3];
  const float* g1  = (const float*)d_in[4];
  const float* be1 = (const float*)d_in[5];
  const float* m1  = (const float*)d_in[6];
  const float* v1  = (const float*)d_in[7];
  const float* w2  = (const float*)d_in[8];
  const float* b2  = (const float*)d_in[9];
  const float* g2  = (const float*)d_in[10];
  const float* be2 = (const float*)d_in[11];
  const float* m2  = (const float*)d_in[12];
  const float* v2  = (const float*)d_in[13];
  const float* w3  = (const float*)d_in[14];
  const float* b3  = (const float*)d_in[15];

  char* ws = (char*)d_ws;
  _Float16* wT1h = (_Float16*)ws;  ws += (size_t)9 * CIN * CIN * 2;
  _Float16* wT2h = (_Float16*)ws;  ws += (size_t)9 * CIN * CIN * 2;
  _Float16* wT3h = (_Float16*)ws;  ws += (size_t)CIN * COUTC * 2;
  _Float16* x0   = (_Float16*)ws;  ws += (size_t)N_IMG * SPH * CIN * 2;
  _Float16* x1h  = (_Float16*)ws;  ws += (size_t)N_IMG * SPH * CIN * 2;
  _Float16* x2h  = (_Float16*)ws;  ws += (size_t)N_IMG * SP * CIN * 2;
  _Float16* feat = (_Float16*)ws;  ws += (size_t)N_IMG * SP * COUTC * 2;
  float*    outp = (float*)d_out;

  prep_misc<<<86, 256, 0, stream>>>(w3, wT3h, x0, x1h);
  prep_w33<<<dim3(256, 2), 256, 0, stream>>>(w1, w2, wT1h, wT2h);
  nchw_to_nhwc<<<dim3(44, 4, 6), 256, 0, stream>>>(img, x0);

  conv3x3_mfma<<<528, 256, 0, stream>>>(x0, wT1h, b1, g1, be1, m1, v1,
                                        x1h, WW, WW + 1, SPH);
  conv3x3_mfma<<<528, 256, 0, stream>>>(x1h, wT2h, b2, g2, be2, m2, v2,
                                        x2h, 88, 0, SP);
  conv1x1_mfma<<<264, 128, 0, stream>>>(x2h, wT3h, b3, feat);

  bev_sample<<<512, 320, 0, stream>>>(feat, l2i, outp);
}

// Round 15
// 211.587 us; speedup vs baseline: 1.7108x; 1.0387x over previous
//
#include <hip/hip_runtime.h>
#include <math.h>

#define N_IMG 6
#define CIN   256
#define H_IN  32
#define W_IN  88
#define SP    2816      // 32*88
#define HH    34        // H+2 halo
#define WW    90        // W+2 halo
#define SPH   3060      // 34*90
#define COUTC 80
#define EPSBN 1e-5f

typedef _Float16 half8 __attribute__((ext_vector_type(8)));
typedef float floatx4 __attribute__((ext_vector_type(4)));

#define AS1 __attribute__((address_space(1)))
#define AS3 __attribute__((address_space(3)))

// ---------------- fused front-end prep ----------------
// blocks 0..511    : w1/w2 (OIHW) -> fp16 [tap][oc][ic]   (layer = bx>>8)
// blocks 512..597  : w3 cast copy (first 80) + halo zero of x0/x1h (last 6)
// blocks 598..1653 : img fp32 NCHW -> fp16 NHWC into halo layout
__global__ __launch_bounds__(256) void prep_all(
    const float* __restrict__ w1, const float* __restrict__ w2,
    _Float16* __restrict__ wT1, _Float16* __restrict__ wT2,
    const float* __restrict__ w3, _Float16* __restrict__ wT3,
    const float* __restrict__ img, _Float16* __restrict__ x0,
    _Float16* __restrict__ x1h)
{
  __shared__ float t[64][65];   // 16.6 KB (union: w33 path uses first 2304 floats)
  const int bx  = blockIdx.x;
  const int tid = threadIdx.x;

  if (bx < 512) {
    // ---- w33 transpose ----
    const int layer = bx >> 8;
    const int oc    = bx & 255;
    const float* w  = layer ? w2 : w1;
    _Float16* wT    = layer ? wT2 : wT1;
    float* s = &t[0][0];
    const float* wo = w + (size_t)oc * 2304;
    for (int i = tid; i < 2304; i += 256) s[i] = wo[i];
    __syncthreads();
    for (int i = tid; i < 2304; i += 256) {
      const int tap = i >> 8;
      const int ic  = i & 255;
      wT[((size_t)tap * 256 + oc) * 256 + ic] = (_Float16)s[ic * 9 + tap];
    }
  } else if (bx < 598) {
    const int b2 = bx - 512;
    if (b2 < 80) {
      const int idx = b2 * 256 + tid;
      wT3[idx] = (_Float16)w3[idx];
    } else {
      const int im = b2 - 80;   // 0..5
      for (int s = tid; s < 244 * 32; s += 256) {
        const int pos = s >> 5;
        const int gr  = s & 31;
        int h, w;
        if (pos < 90)       { h = 0;  w = pos; }
        else if (pos < 180) { h = 33; w = pos - 90; }
        else { const int r = pos - 180; h = 1 + (r >> 1); w = (r & 1) * 89; }
        const size_t off = ((size_t)im * SPH + h * WW + w) * CIN + gr * 8;
        half8 z = {};
        *(half8*)(x0 + off) = z;
        *(half8*)(x1h + off) = z;
      }
    }
  } else {
    // ---- NCHW -> NHWC (halo layout) ----
    const int idx = bx - 598;          // 0..1055
    const int sp0 = (idx % 44) * 64;
    const int ic0 = ((idx / 44) % 4) * 64;
    const int im  = idx / 176;
    const int tx = tid & 63;
    const int ty = tid >> 6;   // 0..3
    for (int r = ty; r < 64; r += 4)
      t[r][tx] = img[((size_t)(im * CIN + ic0 + r)) * SP + sp0 + tx];
    __syncthreads();
    for (int r = ty; r < 64; r += 4) {
      const int sp = sp0 + r;
      const int h = sp / 88;
      const int w = sp - h * 88;
      x0[((size_t)im * SPH + h * WW + w + WW + 1) * CIN + ic0 + tx] = (_Float16)t[tx][r];
    }
  }
}

// ---------------- 3x3 conv + BN + ReLU: dbuf + co-resident MFMA ------------
// [r10, best measured: 43.5 us, 0 conflicts] tile 64(M) x 128(N), grid 528
// (2.06 blocks/CU). 36 chunks BK=64 (tap, ic-quarter). Double-buffered LDS
// (A 8K + B 16K per buf = 48 KB): DMA(c+1) issued right after the barrier,
// compute(c) overlaps; ONE barrier per chunk. XOR-granule swizzle.
__global__ __launch_bounds__(256) void conv3x3_mfma(
    const _Float16* __restrict__ x, const _Float16* __restrict__ wT,
    const float* __restrict__ bias, const float* __restrict__ gamma,
    const float* __restrict__ beta, const float* __restrict__ bnm,
    const float* __restrict__ bnv, _Float16* __restrict__ out,
    int OW, int OB, int imStride)
{
  __shared__ _Float16 As[2][64 * 64];    // 2 x 8 KB
  __shared__ _Float16 Bs[2][128 * 64];   // 2 x 16 KB

  const int tid  = threadIdx.x;
  const int wv   = tid >> 6;
  const int lane = tid & 63;
  const int bx   = blockIdx.x;
  const int n0   = (bx & 1) << 7;
  const int mt   = bx >> 1;            // 0..263
  const int im   = mt / 44;
  const int m0sp = (mt - im * 44) * 64;
  const _Float16* xim = x + (size_t)im * SPH * CIN;

  // staging source offsets (granule XOR swizzle applied on the source)
  int srcA[2], srcB[4];
  #pragma unroll
  for (int i = 0; i < 2; ++i) {
    const int g = i * 256 + wv * 64 + lane;    // 0..511
    const int row = g >> 3;
    const int lg  = (g & 7) ^ (row & 7);
    const int m = m0sp + row;
    const int h = m / 88;
    const int w = m - h * 88;
    srcA[i] = ((h + 1) * WW + (w + 1)) * CIN + lg * 8;
  }
  #pragma unroll
  for (int i = 0; i < 4; ++i) {
    const int g = i * 256 + wv * 64 + lane;    // 0..1023
    const int row = g >> 3;
    const int lg  = (g & 7) ^ (row & 7);
    srcB[i] = (n0 + row) * 256 + lg * 8;
  }

  const int fr = lane & 15;
  const int q  = lane >> 4;        // 0..3
  const int q4 = q * 4;
  const int mw = (wv & 1) * 32;
  const int nw = (wv >> 1) * 64;

  floatx4 acc[2][4];
  #pragma unroll
  for (int i = 0; i < 2; ++i)
    #pragma unroll
    for (int j = 0; j < 4; ++j) {
      acc[i][j][0] = 0.f; acc[i][j][1] = 0.f; acc[i][j][2] = 0.f; acc[i][j][3] = 0.f;
    }

  // prologue: DMA chunk 0 (tap 0: dy=-1,dx=-1; icc=0) into buffer 0
  {
    const int aoff0 = (-1 * WW - 1) * CIN;
    #pragma unroll
    for (int i = 0; i < 2; ++i)
      __builtin_amdgcn_global_load_lds(
          (const AS1 void*)(xim + srcA[i] + aoff0),
          (AS3 void*)(&As[0][(i * 256 + wv * 64) * 8]), 16, 0, 0);
    #pragma unroll
    for (int i = 0; i < 4; ++i)
      __builtin_amdgcn_global_load_lds(
          (const AS1 void*)(wT + srcB[i]),
          (AS3 void*)(&Bs[0][(i * 256 + wv * 64) * 8]), 16, 0, 0);
  }

  for (int c = 0; c < 36; ++c) {
    __syncthreads();   // drains DMA(c); all waves done reading buf (c+1)&1
    if (c < 35) {
      const int cn   = c + 1;
      const int tapn = cn >> 2;
      const int iccn = (cn & 3) << 6;
      const int dyn  = tapn / 3 - 1;
      const int dxn  = tapn - (tapn / 3) * 3 - 1;
      const int aoffn = (dyn * WW + dxn) * CIN + iccn;
      const size_t boffn = (size_t)tapn * 65536 + iccn;
      const int nb = cn & 1;
      #pragma unroll
      for (int i = 0; i < 2; ++i)
        __builtin_amdgcn_global_load_lds(
            (const AS1 void*)(xim + srcA[i] + aoffn),
            (AS3 void*)(&As[nb][(i * 256 + wv * 64) * 8]), 16, 0, 0);
      #pragma unroll
      for (int i = 0; i < 4; ++i)
        __builtin_amdgcn_global_load_lds(
            (const AS1 void*)(wT + boffn + srcB[i]),
            (AS3 void*)(&Bs[nb][(i * 256 + wv * 64) * 8]), 16, 0, 0);
    }
    const int cb = c & 1;
    #pragma unroll
    for (int ks = 0; ks < 2; ++ks) {
      half8 af[2], bf[4];
      #pragma unroll
      for (int i = 0; i < 2; ++i) {
        const int row = mw + i * 16 + fr;
        af[i] = *(const half8*)(&As[cb][row * 64 + (((ks * 4 + q) ^ (row & 7)) * 8)]);
      }
      #pragma unroll
      for (int j = 0; j < 4; ++j) {
        const int row = nw + j * 16 + fr;
        bf[j] = *(const half8*)(&Bs[cb][row * 64 + (((ks * 4 + q) ^ (row & 7)) * 8)]);
      }
      #pragma unroll
      for (int i = 0; i < 2; ++i)
        #pragma unroll
        for (int j = 0; j < 4; ++j)
          acc[i][j] = __builtin_amdgcn_mfma_f32_16x16x32_f16(af[i], bf[j], acc[i][j], 0, 0, 0);
    }
  }

  // epilogue: BN + ReLU, store fp16 NHWC (halo or flat per OW/OB/imStride)
  #pragma unroll
  for (int j = 0; j < 4; ++j) {
    const int oc = n0 + nw + j * 16 + fr;
    const float sc = gamma[oc] * rsqrtf(bnv[oc] + EPSBN);
    const float sh = (bias[oc] - bnm[oc]) * sc + beta[oc];
    #pragma unroll
    for (int i = 0; i < 2; ++i) {
      #pragma unroll
      for (int r = 0; r < 4; ++r) {
        const int m = m0sp + mw + i * 16 + q4 + r;
        const int h = m / 88;
        const int w = m - h * 88;
        const float v = fmaxf(fmaf(acc[i][j][r], sc, sh), 0.f);
        out[((size_t)im * imStride + h * OW + w + OB) * CIN + oc] = (_Float16)v;
      }
    }
  }
}

// ---------------- 1x1 conv (256->80) + bias, fp16 MFMA, NHWC fp16 out --------
__global__ __launch_bounds__(128) void conv1x1_mfma(
    const _Float16* __restrict__ x, const _Float16* __restrict__ wT,
    const float* __restrict__ bias, _Float16* __restrict__ feat)
{
  __shared__ _Float16 Bs[80 * 264];   // [oc][ic 256 + pad 8]

  const int tid = threadIdx.x;
  const int m0  = blockIdx.x * 64;
  const int wv   = tid >> 6;
  const int lane = tid & 63;
  const int fr  = lane & 15;
  const int q8  = (lane >> 4) * 8;
  const int q4  = (lane >> 4) * 4;

  for (int g = tid; g < 2560; g += 128) {
    const int oc = g >> 5;
    const int kg8 = (g & 31) << 3;
    *(half8*)(&Bs[oc * 264 + kg8]) = *(const half8*)(wT + oc * 256 + kg8);
  }
  __syncthreads();

  floatx4 acc[2][5];
  #pragma unroll
  for (int i = 0; i < 2; ++i)
    #pragma unroll
    for (int j = 0; j < 5; ++j) {
      acc[i][j][0] = 0.f; acc[i][j][1] = 0.f; acc[i][j][2] = 0.f; acc[i][j][3] = 0.f;
    }

  const _Float16* xa = x + (size_t)(m0 + wv * 32 + fr) * 256 + q8;
  #pragma unroll
  for (int ks = 0; ks < 8; ++ks) {
    half8 af[2], bf[5];
    #pragma unroll
    for (int i = 0; i < 2; ++i)
      af[i] = *(const half8*)(xa + (size_t)i * 16 * 256 + ks * 32);
    #pragma unroll
    for (int j = 0; j < 5; ++j)
      bf[j] = *(const half8*)(&Bs[(j * 16 + fr) * 264 + ks * 32 + q8]);
    #pragma unroll
    for (int i = 0; i < 2; ++i)
      #pragma unroll
      for (int j = 0; j < 5; ++j)
        acc[i][j] = __builtin_amdgcn_mfma_f32_16x16x32_f16(af[i], bf[j], acc[i][j], 0, 0, 0);
  }

  #pragma unroll
  for (int j = 0; j < 5; ++j) {
    const int oc = j * 16 + fr;
    const float bb = bias[oc];
    #pragma unroll
    for (int i = 0; i < 2; ++i) {
      const int mbase = m0 + wv * 32 + i * 16 + q4;
      #pragma unroll
      for (int r = 0; r < 4; ++r)
        feat[(size_t)(mbase + r) * COUTC + oc] = (_Float16)(acc[i][j][r] + bb);
    }
  }
}

// ---------------- projection + bilinear + max(cams) + mean(z), fused T ------
// block: 320 threads = 32 cells x 10 channel-groups (8 ch each, half8 loads).
// Writes out[c][cell] (transposed) directly — no separate transpose kernel.
__global__ __launch_bounds__(320) void bev_sample(
    const _Float16* __restrict__ feat, const float* __restrict__ l2i,
    float* __restrict__ outp)
{
  __shared__ int4   eo[1920];
  __shared__ float4 ew[1920];
  const int tid = threadIdx.x;
  const int cellBase = blockIdx.x * 32;

  for (int e = tid; e < 1920; e += 320) {
    const int cell = e / 60;
    const int idx = e - cell * 60;
    const int n = idx / 10;
    const int z = idx - n * 10;
    const int cid = cellBase + cell;
    const int gix = cid >> 7;
    const int giy = cid & 127;
    const float X = (float)(-50.8 + (double)gix * (101.6 / 127.0));
    const float Y = (float)(-50.8 + (double)giy * (101.6 / 127.0));
    const float Z = (float)(-4.6 + (double)z * (7.2 / 9.0));
    const float* M = l2i + n * 16;
    const float pw = M[0] * X + M[1] * Y + M[2] * Z + M[3];
    const float ph = M[4] * X + M[5] * Y + M[6] * Z + M[7];
    const float d  = M[8] * X + M[9] * Y + M[10] * Z + M[11];
    const float px = pw / d;
    const float py = ph / d;
    const bool on_img = (px < 704.f) && (px > 0.f) && (py < 256.f) && (py > 0.f) && (d > 0.1f);
    const float gx = px / 704.f * 2.f - 1.f;
    const float gy = py / 256.f * 2.f - 1.f;
    const float ixf = (gx + 1.f) * 0.5f * 87.f;
    const float iyf = (gy + 1.f) * 0.5f * 31.f;
    const float ix0 = floorf(ixf);
    const float iy0 = floorf(iyf);
    const float wx1 = ixf - ix0;
    const float wy1 = iyf - iy0;
    const float ix1 = ix0 + 1.f, iy1 = iy0 + 1.f;
    float w00 = (1.f - wy1) * (1.f - wx1);
    float w01 = (1.f - wy1) * wx1;
    float w10 = wy1 * (1.f - wx1);
    float w11 = wy1 * wx1;
    const bool vx0 = (ix0 >= 0.f) && (ix0 < 88.f);
    const bool vx1 = (ix1 >= 0.f) && (ix1 < 88.f);
    const bool vy0 = (iy0 >= 0.f) && (iy0 < 32.f);
    const bool vy1 = (iy1 >= 0.f) && (iy1 < 32.f);
    if (!(on_img && vy0 && vx0)) w00 = 0.f;
    if (!(on_img && vy0 && vx1)) w01 = 0.f;
    if (!(on_img && vy1 && vx0)) w10 = 0.f;
    if (!(on_img && vy1 && vx1)) w11 = 0.f;
    const int i0 = (int)fminf(fmaxf(ix0, 0.f), 87.f);
    const int i1 = (int)fminf(fmaxf(ix1, 0.f), 87.f);
    const int j0 = (int)fminf(fmaxf(iy0, 0.f), 31.f);
    const int j1 = (int)fminf(fmaxf(iy1, 0.f), 31.f);
    const int base = n * SP;
    eo[e] = make_int4((base + j0 * 88 + i0) * COUTC,
                      (base + j0 * 88 + i1) * COUTC,
                      (base + j1 * 88 + i0) * COUTC,
                      (base + j1 * 88 + i1) * COUTC);
    ew[e] = make_float4(w00, w01, w10, w11);
  }
  __syncthreads();

  const int grp  = tid % 10;
  const int c8   = grp * 8;
  const int cell = tid / 10;
  const int ebase = cell * 60;
  float acc[8];
  #pragma unroll
  for (int k = 0; k < 8; ++k) acc[k] = 0.f;

  for (int z = 0; z < 10; ++z) {
    float mx[8];
    #pragma unroll
    for (int k = 0; k < 8; ++k) mx[k] = -INFINITY;
    #pragma unroll
    for (int n = 0; n < 6; ++n) {
      const float4 w = ew[ebase + n * 10 + z];
      if (w.x + w.y + w.z + w.w > 0.f) {
        const int4 o = eo[ebase + n * 10 + z];
        const half8 p00 = *(const half8*)(feat + o.x + c8);
        const half8 p01 = *(const half8*)(feat + o.y + c8);
        const half8 p10 = *(const half8*)(feat + o.z + c8);
        const half8 p11 = *(const half8*)(feat + o.w + c8);
        #pragma unroll
        for (int k = 0; k < 8; ++k) {
          float v = w.x * (float)p00[k];
          v = fmaf(w.y, (float)p01[k], v);
          v = fmaf(w.z, (float)p10[k], v);
          v = fmaf(w.w, (float)p11[k], v);
          mx[k] = fmaxf(mx[k], v);
        }
      } else {
        #pragma unroll
        for (int k = 0; k < 8; ++k) mx[k] = fmaxf(mx[k], 0.f);
      }
    }
    #pragma unroll
    for (int k = 0; k < 8; ++k) acc[k] += mx[k];
  }
  const int cid = cellBase + cell;
  #pragma unroll
  for (int k = 0; k < 8; ++k)
    outp[(size_t)(c8 + k) * 16384 + cid] = acc[k] * 0.1f;
}

extern "C" void kernel_launch(void* const* d_in, const int* in_sizes, int n_in,
                              void* d_out, int out_size, void* d_ws, size_t ws_size,
                              hipStream_t stream)
{
  const float* img = (const float*)d_in[0];
  const float* l2i = (const float*)d_in[1];
  const float* w1  = (const float*)d_in[2];
  const float* b1  = (const float*)d_in[3];
  const float* g1  = (const float*)d_in[4];
  const float* be1 = (const float*)d_in[5];
  const float* m1  = (const float*)d_in[6];
  const float* v1  = (const float*)d_in[7];
  const float* w2  = (const float*)d_in[8];
  const float* b2  = (const float*)d_in[9];
  const float* g2  = (const float*)d_in[10];
  const float* be2 = (const float*)d_in[11];
  const float* m2  = (const float*)d_in[12];
  const float* v2  = (const float*)d_in[13];
  const float* w3  = (const float*)d_in[14];
  const float* b3  = (const float*)d_in[15];

  char* ws = (char*)d_ws;
  _Float16* wT1h = (_Float16*)ws;  ws += (size_t)9 * CIN * CIN * 2;
  _Float16* wT2h = (_Float16*)ws;  ws += (size_t)9 * CIN * CIN * 2;
  _Float16* wT3h = (_Float16*)ws;  ws += (size_t)CIN * COUTC * 2;
  _Float16* x0   = (_Float16*)ws;  ws += (size_t)N_IMG * SPH * CIN * 2;
  _Float16* x1h  = (_Float16*)ws;  ws += (size_t)N_IMG * SPH * CIN * 2;
  _Float16* x2h  = (_Float16*)ws;  ws += (size_t)N_IMG * SP * CIN * 2;
  _Float16* feat = (_Float16*)ws;  ws += (size_t)N_IMG * SP * COUTC * 2;
  float*    outp = (float*)d_out;

  prep_all<<<1654, 256, 0, stream>>>(w1, w2, wT1h, wT2h, w3, wT3h, img, x0, x1h);

  conv3x3_mfma<<<528, 256, 0, stream>>>(x0, wT1h, b1, g1, be1, m1, v1,
                                        x1h, WW, WW + 1, SPH);
  conv3x3_mfma<<<528, 256, 0, stream>>>(x1h, wT2h, b2, g2, be2, m2, v2,
                                        x2h, 88, 0, SP);
  conv1x1_mfma<<<264, 128, 0, stream>>>(x2h, wT3h, b3, feat);

  bev_sample<<<512, 320, 0, stream>>>(feat, l2i, outp);
}